// Round 17
// baseline (924.064 us; speedup 1.0000x reference)
//
#include <hip/hip_runtime.h>
#include <math.h>

// GCN generator: B=8, N=F=128. One block/batch, 1024 threads (16 waves).
// Round 17: round 13 (541us) EXACTLY, one change: the P4 tail's row reads
// are chunk-ROTATED by (tt>>3) so the 8 lanes {tt, tt+8, ...} that share a
// bank-span at stride 272B read 8 DIFFERENT chunks each step -> conflict-
// free (was 8-way on all 32 b128 reads). Zero new register state (r14/15/16
// all spilled: r13 peak pressure == the 64-VGPR budget).
//   P2: z^T=(U*dcv).Gc-rows; carry quarter ks==wr; eps: z=dn*acc+bias, relu,
//       f16x4->X, ssq (2-shfl)
//   P4: mm_a u=(dv.z).W -> U + t<128 tail: rotated prob dots, sigmoid,
//       out writes, Gn row/col-pn patches
//   P4c: t<128: sp butterfly, degrees, diag track, stored diag = dgC+1.

#define NN 128
#define SP 136

typedef _Float16 f16;
typedef _Float16 f16x8 __attribute__((ext_vector_type(8)));
typedef _Float16 f16x4 __attribute__((ext_vector_type(4)));
typedef _Float16 f16x2 __attribute__((ext_vector_type(2)));
typedef float f32x4 __attribute__((ext_vector_type(4)));

__device__ __forceinline__ f32x4 mm(f16x8 a, f16x8 b, f32x4 c) {
    return __builtin_amdgcn_mfma_f32_16x16x32_f16(a, b, c, 0, 0, 0);
}

__device__ __forceinline__ float rowdot8(f16x8 g, float acc) {
#if __has_builtin(__builtin_amdgcn_fdot2)
    const f16x2 one2 = {(f16)1.0f, (f16)1.0f};
    #pragma unroll
    for (int p = 0; p < 4; ++p) {
        f16x2 pr = {g[2*p], g[2*p+1]};
        acc = __builtin_amdgcn_fdot2(pr, one2, acc, false);
    }
#else
    #pragma unroll
    for (int e = 0; e < 8; ++e) acc += (float)g[e];
#endif
    return acc;
}

__device__ __forceinline__ float dot8(f16x8 a, f16x8 b, float acc) {
#if __has_builtin(__builtin_amdgcn_fdot2)
    #pragma unroll
    for (int p = 0; p < 4; ++p) {
        f16x2 pa = {a[2*p], a[2*p+1]};
        f16x2 pb = {b[2*p], b[2*p+1]};
        acc = __builtin_amdgcn_fdot2(pa, pb, acc, false);
    }
#else
    #pragma unroll
    for (int e = 0; e < 8; ++e) acc += (float)a[e]*(float)b[e];
#endif
    return acc;
}

__global__ __launch_bounds__(1024)
void gcn_gen_kernel(const float* __restrict__ gx,
                    const float* __restrict__ gW,
                    const float* __restrict__ gb,
                    float* __restrict__ gout)
{
    extern __shared__ char lds_raw[];
    f16* X     = (f16*)lds_raw;              // [128][136] UNNORM z [n][f]
    f16* U     = X + NN*SP;                  // [128][136] u = x_hat.W, [fo][m]
    f16* Gb0   = U + NN*SP;                  // [128][136] M-hat' ping (diag+1)
    f16* Gb1   = Gb0 + NN*SP;                // [128][136] M-hat' pong
    f16* s_df16  = Gb1 + NN*SP;              // [128] d (f16)
    float* s_d    = (float*)(s_df16 + NN);   // [128] d (f32)
    float* s_diag = s_d + NN;                // [128] diag of carried C
    float* s_prob = s_diag + NN;             // [128] probs this step
    float* s_rows = s_prob + NN;             // [4][128] rowsum quarters (by wr)
    float* s_ssq  = s_rows + 4*NN;           // [4][128] ssq partials (by wr)

    const int b = blockIdx.x;
    const int t = threadIdx.x;
    const int lane = t & 63;
    const int w = t >> 6;
    const int wr = w >> 2, wc = w & 3;       // wave grid: wr=fo-block, wc=n-block
    const int lrow = lane & 15;
    const int lgrp = lane >> 4;
    const int r0 = wr*32 + lrow;             // A-row for mm_a / U-row for mm_b
    const int r1 = r0 + 16;
    const int n0 = wc*32 + lrow;             // Gc/X n-row for mm_b B-side
    const int n1 = n0 + 16;

    const float* xb = gx + (size_t)b*NN*NN;
    float* outb = gout + (size_t)b*NN*NN;

    // bias indexed by fo = wr*32 + rt*16 + lgrp*4 + q
    const float4 bv0 = *(const float4*)(gb + wr*32 + lgrp*4);
    const float4 bv1 = *(const float4*)(gb + wr*32 + 16 + lgrp*4);

    // ---- W -> registers as B-fragments for mm_a (k=fi, col=fo) ----
    f16x8 Wh[4][2];
    #pragma unroll
    for (int ks = 0; ks < 4; ++ks)
    #pragma unroll
    for (int ct = 0; ct < 2; ++ct) {
        const int col = wc*32 + ct*16 + lrow;
        #pragma unroll
        for (int r = 0; r < 8; ++r)
            Wh[ks][ct][r] = (f16)gW[(ks*32 + lgrp*8 + r)*NN + col];
    }

    // ---- init: X = f16(x), G0 = I with diag 2.0 (+I fold), out = eye ----
    #pragma unroll
    for (int q = 0; q < 16; ++q) {
        int idx = q*1024 + t;
        int r = idx >> 7, c = idx & 127;
        float e = (r == c) ? 1.f : 0.f;
        X[r*SP + c] = (f16)xb[idx];
        Gb0[r*SP + c] = (f16)(e * 2.f);      // M' = I + I
        outb[idx] = e;
    }
    if (t < NN) {
        s_d[t] = 0.70710678f;
        s_df16[t] = (f16)0.70710678f;
        s_diag[t] = 1.f;                     // diag(C_0) = 1
    }
    __syncthreads();

    // mm_a: u = (sv . X) . W -> U[fo][m]
    auto run_mma = [&](f16 sv0, f16 sv1) {
        f32x4 a2[2][2];
        #pragma unroll
        for (int rt = 0; rt < 2; ++rt)
        #pragma unroll
        for (int ct = 0; ct < 2; ++ct)
            a2[rt][ct] = (f32x4){0.f,0.f,0.f,0.f};
        #pragma unroll
        for (int ks = 0; ks < 4; ++ks) {
            const int ko = ks*32 + lgrp*8;
            f16x8 A0 = *(const f16x8*)(X + r0*SP + ko) * sv0;
            f16x8 A1 = *(const f16x8*)(X + r1*SP + ko) * sv1;
            a2[0][0] = mm(A0, Wh[ks][0], a2[0][0]);
            a2[0][1] = mm(A0, Wh[ks][1], a2[0][1]);
            a2[1][0] = mm(A1, Wh[ks][0], a2[1][0]);
            a2[1][1] = mm(A1, Wh[ks][1], a2[1][1]);
        }
        #pragma unroll
        for (int rt = 0; rt < 2; ++rt)
        #pragma unroll
        for (int ct = 0; ct < 2; ++ct) {
            f16x4 uv;
            #pragma unroll
            for (int q = 0; q < 4; ++q) uv[q] = (f16)a2[rt][ct][q];
            *(f16x4*)(U + (wc*32 + ct*16 + lrow)*SP + wr*32 + rt*16 + lgrp*4) = uv;
        }
    };
    run_mma((f16)1.0f, (f16)1.0f);
    __syncthreads();

    for (int i = 0; i < NN; ++i) {
        const int pn = i + 1;
        f16* Gc = (i & 1) ? Gb1 : Gb0;       // M-hat' (patched, diag = dgC+1)
        f16* Gn = (i & 1) ? Gb0 : Gb1;       // receives scaled carry

        // ========== P2: z^T = (U*dcv) . Gc-rows; carry; epilogue ==========
        f16x8 dcv[4];
        #pragma unroll
        for (int ks = 0; ks < 4; ++ks)
            dcv[ks] = *(const f16x8*)(s_df16 + ks*32 + lgrp*8);
        const f16 dn0h = s_df16[n0];
        const f16 dn1h = s_df16[n1];

        f32x4 acc[2][2];                     // [rt=fo][ct=n]
        #pragma unroll
        for (int rt = 0; rt < 2; ++rt)
        #pragma unroll
        for (int ct = 0; ct < 2; ++ct)
            acc[rt][ct] = (f32x4){0.f,0.f,0.f,0.f};
        float rs0 = 0.f, rs1 = 0.f;
        #pragma unroll
        for (int ks = 0; ks < 4; ++ks) {
            const int ko = ks*32 + lgrp*8;
            f16x8 A0 = *(const f16x8*)(U + r0*SP + ko) * dcv[ks];
            f16x8 A1 = *(const f16x8*)(U + r1*SP + ko) * dcv[ks];
            f16x8 B0 = *(const f16x8*)(Gc + n0*SP + ko);
            f16x8 B1 = *(const f16x8*)(Gc + n1*SP + ko);
            acc[0][0] = mm(A0, B0, acc[0][0]);
            acc[0][1] = mm(A0, B1, acc[0][1]);
            acc[1][0] = mm(A1, B0, acc[1][0]);
            acc[1][1] = mm(A1, B1, acc[1][1]);
            if (ks == wr) {                  // own (n in wc, k in wr) quarter
                f16x8 G0s = B0 * dcv[ks] * dn0h;
                f16x8 G1s = B1 * dcv[ks] * dn1h;
                *(f16x8*)(Gn + n0*SP + ko) = G0s;
                *(f16x8*)(Gn + n1*SP + ko) = G1s;
                rs0 = rowdot8(G0s, rs0);
                rs1 = rowdot8(G1s, rs1);
            }
        }
        rs0 += __shfl_xor(rs0, 16); rs0 += __shfl_xor(rs0, 32);
        rs1 += __shfl_xor(rs1, 16); rs1 += __shfl_xor(rs1, 32);
        if (lgrp == 0) {
            s_rows[wr*NN + n0] = rs0;
            s_rows[wr*NN + n1] = rs1;
        }

        // epilogue: z = dn * acc + bias(fo), relu; f16x4 -> X; ssq
        const float dn[2] = { s_d[n0], s_d[n1] };
        float ssc[2] = {0.f, 0.f};
        #pragma unroll
        for (int rt = 0; rt < 2; ++rt)
        #pragma unroll
        for (int ct = 0; ct < 2; ++ct) {
            f16x4 xv;
            #pragma unroll
            for (int q = 0; q < 4; ++q) {
                float bq = rt ? ((const float*)&bv1)[q] : ((const float*)&bv0)[q];
                float zv = fmaxf(fmaf(dn[ct], acc[rt][ct][q], bq), 0.f);
                ssc[ct] = fmaf(zv, zv, ssc[ct]);
                xv[q] = (f16)zv;
            }
            *(f16x4*)(X + (wc*32 + ct*16 + lrow)*SP + wr*32 + rt*16 + lgrp*4) = xv;
        }
        ssc[0] += __shfl_xor(ssc[0], 16); ssc[0] += __shfl_xor(ssc[0], 32);
        ssc[1] += __shfl_xor(ssc[1], 16); ssc[1] += __shfl_xor(ssc[1], 32);
        if (lgrp == 0) {
            s_ssq[wr*NN + n0] = ssc[0];
            s_ssq[wr*NN + n1] = ssc[1];
        }
        __syncthreads();

        // ========== P4: mm_a (dv-scaled) + t<128 tail (rotated reads) =====
        float p_keep = 0.f;
        if (pn < NN) {
            f16 dvh[2];
            #pragma unroll
            for (int rt = 0; rt < 2; ++rt) {
                const int row = wr*32 + rt*16 + lrow;
                float sq = s_ssq[row] + s_ssq[NN+row] + s_ssq[2*NN+row] + s_ssq[3*NN+row];
                float dv = (i == 0) ? 1.f : 1.f/(sqrtf(sq) + 1e-8f);
                dvh[rt] = (f16)fminf(dv, 60000.f);
            }
            run_mma(dvh[0], dvh[1]);

            if (t < NN) {
                const int tt = t;
                float sqp = s_ssq[pn] + s_ssq[NN+pn] + s_ssq[2*NN+pn] + s_ssq[3*NN+pn];
                float dp = (i == 0) ? 1.f : 1.f/(sqrtf(sqp) + 1e-8f);
                if (tt < pn) {
                    const f16x8* Xr = (const f16x8*)(X + tt*SP);
                    const f16x8* Xp = (const f16x8*)(X + pn*SP);
                    const int rot = (tt >> 3) & 15;   // bank-spread rotation
                    float a0 = 0.f, a1 = 0.f, a2v = 0.f, a3 = 0.f;
                    #pragma unroll
                    for (int m = 0; m < 16; ++m) {
                        const int ci = (m + rot) & 15;
                        float v = dot8(Xr[ci], Xp[ci], 0.f);
                        if ((m & 3) == 0) a0 += v;
                        else if ((m & 3) == 1) a1 += v;
                        else if ((m & 3) == 2) a2v += v;
                        else a3 += v;
                    }
                    float zd = (a0 + a1) + (a2v + a3);
                    float sqj = s_ssq[tt] + s_ssq[NN+tt] + s_ssq[2*NN+tt] + s_ssq[3*NN+tt];
                    float dj = (i == 0) ? 1.f : 1.f/(sqrtf(sqj) + 1e-8f);
                    p_keep = 1.f/(1.f + expf(-0.5f*zd*dj*dp));
                    f16 pf = (f16)p_keep;
                    outb[pn*NN + tt] = p_keep;
                    outb[tt*NN + pn] = p_keep;
                    Gn[pn*SP + tt] = pf;     // patch row pn
                    Gn[tt*SP + pn] = pf;     // patch col pn
                }
                s_prob[tt] = p_keep;
            }
        }
        __syncthreads();

        // ========== P4c: degrees/diag (t<128) ==========
        if (pn < NN && t < NN) {
            const int tt = t;
            float pa = s_prob[lane];
            float pb = s_prob[lane + 64];
            float sp = ((lane < pn) ? pa : 0.f) + ((lane + 64 < pn) ? pb : 0.f);
            #pragma unroll
            for (int m2 = 1; m2 < 64; m2 <<= 1) sp += __shfl_xor(sp, m2);
            // rowsum(C_i) = local (carry diag auto-correct with +I fold)
            float rsC = s_rows[tt] + s_rows[NN+tt] + s_rows[2*NN+tt] + s_rows[3*NN+tt];
            float dgC = s_diag[tt];                   // diag(C_i)_t
            float rsM = (tt < pn) ? (rsC + p_keep)
                      : ((tt == pn) ? (sp + dgC) : rsC);
            float dnew = 1.f/sqrtf(rsM + 1.f + 1e-8f);
            s_d[tt] = dnew;
            s_df16[tt] = (f16)dnew;
            s_diag[tt] = dnew*dnew*(dgC + 1.f);       // diag(C_{i+1})
            Gn[tt*SP + tt] = (f16)(dgC + 1.f);        // stored diag = dgC+1
        }
        __syncthreads();
    }
}

extern "C" void kernel_launch(void* const* d_in, const int* in_sizes, int n_in,
                              void* d_out, int out_size, void* d_ws, size_t ws_size,
                              hipStream_t stream) {
    const float* x  = (const float*)d_in[0];
    const float* W  = (const float*)d_in[1];
    const float* bb = (const float*)d_in[2];
    float* out = (float*)d_out;

    const size_t shmem = (size_t)(4*NN*SP + NN)*sizeof(f16)
                       + (size_t)(3*NN + 4*NN + 4*NN)*sizeof(float);
    hipFuncSetAttribute((const void*)gcn_gen_kernel,
                        hipFuncAttributeMaxDynamicSharedMemorySize, (int)shmem);
    gcn_gen_kernel<<<8, 1024, shmem, stream>>>(x, W, bb, out);
}

// Round 18
// 541.210 us; speedup vs baseline: 1.7074x; 1.7074x over previous
//
#include <hip/hip_runtime.h>
#include <math.h>

// GCN generator: B=8, N=F=128. One block/batch, 1024 threads (16 waves).
// Round 18 = round 13 VERBATIM (session best, 541us). Rounds 14-17 each
// tried to remove the P4 serial-dot tail or its bank conflicts; all four
// spilled (r13's peak register pressure == the 64-VGPR allocation point;
// WRITE_SIZE 736->2080..4968 KB signature) or added DS-pipe pressure (r12).
// Structure:
//   P2: z^T=(U*dcv).Gc-rows (mm_b via C symmetry); carry quarter ks==wr;
//       epilogue z=dn*acc+bias, relu, f16x4->X, ssq (2-shfl)
//   P4: mm_a u=(dv.z).W -> U (16 waves) + t<128 tail: prob dots, sigmoid,
//       out writes, Gn row/col-pn patches
//   P4c: t<128: sp butterfly, degrees, diag track, stored diag = dgC+1.
// Invariants found this session (violate -> 2x slowdown):
//   - no persistent reg state beyond Wh's 32 VGPRs (r3/r10)
//   - no reg state live across a barrier or extra state across MFMA loops
//     (r14/r15/r16/r17)
//   - serial tails belong in dedicated waves, not on the DS pipe (r12)
//   - G in LDS beats G in global ws (r11)

#define NN 128
#define SP 136

typedef _Float16 f16;
typedef _Float16 f16x8 __attribute__((ext_vector_type(8)));
typedef _Float16 f16x4 __attribute__((ext_vector_type(4)));
typedef _Float16 f16x2 __attribute__((ext_vector_type(2)));
typedef float f32x4 __attribute__((ext_vector_type(4)));

__device__ __forceinline__ f32x4 mm(f16x8 a, f16x8 b, f32x4 c) {
    return __builtin_amdgcn_mfma_f32_16x16x32_f16(a, b, c, 0, 0, 0);
}

__device__ __forceinline__ float rowdot8(f16x8 g, float acc) {
#if __has_builtin(__builtin_amdgcn_fdot2)
    const f16x2 one2 = {(f16)1.0f, (f16)1.0f};
    #pragma unroll
    for (int p = 0; p < 4; ++p) {
        f16x2 pr = {g[2*p], g[2*p+1]};
        acc = __builtin_amdgcn_fdot2(pr, one2, acc, false);
    }
#else
    #pragma unroll
    for (int e = 0; e < 8; ++e) acc += (float)g[e];
#endif
    return acc;
}

__device__ __forceinline__ float dot8(f16x8 a, f16x8 b, float acc) {
#if __has_builtin(__builtin_amdgcn_fdot2)
    #pragma unroll
    for (int p = 0; p < 4; ++p) {
        f16x2 pa = {a[2*p], a[2*p+1]};
        f16x2 pb = {b[2*p], b[2*p+1]};
        acc = __builtin_amdgcn_fdot2(pa, pb, acc, false);
    }
#else
    #pragma unroll
    for (int e = 0; e < 8; ++e) acc += (float)a[e]*(float)b[e];
#endif
    return acc;
}

__global__ __launch_bounds__(1024)
void gcn_gen_kernel(const float* __restrict__ gx,
                    const float* __restrict__ gW,
                    const float* __restrict__ gb,
                    float* __restrict__ gout)
{
    extern __shared__ char lds_raw[];
    f16* X     = (f16*)lds_raw;              // [128][136] UNNORM z [n][f]
    f16* U     = X + NN*SP;                  // [128][136] u = x_hat.W, [fo][m]
    f16* Gb0   = U + NN*SP;                  // [128][136] M-hat' ping (diag+1)
    f16* Gb1   = Gb0 + NN*SP;                // [128][136] M-hat' pong
    f16* s_df16  = Gb1 + NN*SP;              // [128] d (f16)
    float* s_d    = (float*)(s_df16 + NN);   // [128] d (f32)
    float* s_diag = s_d + NN;                // [128] diag of carried C
    float* s_prob = s_diag + NN;             // [128] probs this step
    float* s_rows = s_prob + NN;             // [4][128] rowsum quarters (by wr)
    float* s_ssq  = s_rows + 4*NN;           // [4][128] ssq partials (by wr)

    const int b = blockIdx.x;
    const int t = threadIdx.x;
    const int lane = t & 63;
    const int w = t >> 6;
    const int wr = w >> 2, wc = w & 3;       // wave grid: wr=fo-block, wc=n-block
    const int lrow = lane & 15;
    const int lgrp = lane >> 4;
    const int r0 = wr*32 + lrow;             // A-row for mm_a / U-row for mm_b
    const int r1 = r0 + 16;
    const int n0 = wc*32 + lrow;             // Gc/X n-row for mm_b B-side
    const int n1 = n0 + 16;

    const float* xb = gx + (size_t)b*NN*NN;
    float* outb = gout + (size_t)b*NN*NN;

    // bias indexed by fo = wr*32 + rt*16 + lgrp*4 + q
    const float4 bv0 = *(const float4*)(gb + wr*32 + lgrp*4);
    const float4 bv1 = *(const float4*)(gb + wr*32 + 16 + lgrp*4);

    // ---- W -> registers as B-fragments for mm_a (k=fi, col=fo) ----
    f16x8 Wh[4][2];
    #pragma unroll
    for (int ks = 0; ks < 4; ++ks)
    #pragma unroll
    for (int ct = 0; ct < 2; ++ct) {
        const int col = wc*32 + ct*16 + lrow;
        #pragma unroll
        for (int r = 0; r < 8; ++r)
            Wh[ks][ct][r] = (f16)gW[(ks*32 + lgrp*8 + r)*NN + col];
    }

    // ---- init: X = f16(x), G0 = I with diag 2.0 (+I fold), out = eye ----
    #pragma unroll
    for (int q = 0; q < 16; ++q) {
        int idx = q*1024 + t;
        int r = idx >> 7, c = idx & 127;
        float e = (r == c) ? 1.f : 0.f;
        X[r*SP + c] = (f16)xb[idx];
        Gb0[r*SP + c] = (f16)(e * 2.f);      // M' = I + I
        outb[idx] = e;
    }
    if (t < NN) {
        s_d[t] = 0.70710678f;
        s_df16[t] = (f16)0.70710678f;
        s_diag[t] = 1.f;                     // diag(C_0) = 1
    }
    __syncthreads();

    // mm_a: u = (sv . X) . W -> U[fo][m]
    auto run_mma = [&](f16 sv0, f16 sv1) {
        f32x4 a2[2][2];
        #pragma unroll
        for (int rt = 0; rt < 2; ++rt)
        #pragma unroll
        for (int ct = 0; ct < 2; ++ct)
            a2[rt][ct] = (f32x4){0.f,0.f,0.f,0.f};
        #pragma unroll
        for (int ks = 0; ks < 4; ++ks) {
            const int ko = ks*32 + lgrp*8;
            f16x8 A0 = *(const f16x8*)(X + r0*SP + ko) * sv0;
            f16x8 A1 = *(const f16x8*)(X + r1*SP + ko) * sv1;
            a2[0][0] = mm(A0, Wh[ks][0], a2[0][0]);
            a2[0][1] = mm(A0, Wh[ks][1], a2[0][1]);
            a2[1][0] = mm(A1, Wh[ks][0], a2[1][0]);
            a2[1][1] = mm(A1, Wh[ks][1], a2[1][1]);
        }
        #pragma unroll
        for (int rt = 0; rt < 2; ++rt)
        #pragma unroll
        for (int ct = 0; ct < 2; ++ct) {
            f16x4 uv;
            #pragma unroll
            for (int q = 0; q < 4; ++q) uv[q] = (f16)a2[rt][ct][q];
            *(f16x4*)(U + (wc*32 + ct*16 + lrow)*SP + wr*32 + rt*16 + lgrp*4) = uv;
        }
    };
    run_mma((f16)1.0f, (f16)1.0f);
    __syncthreads();

    for (int i = 0; i < NN; ++i) {
        const int pn = i + 1;
        f16* Gc = (i & 1) ? Gb1 : Gb0;       // M-hat' (patched, diag = dgC+1)
        f16* Gn = (i & 1) ? Gb0 : Gb1;       // receives scaled carry

        // ========== P2: z^T = (U*dcv) . Gc-rows; carry; epilogue ==========
        f16x8 dcv[4];
        #pragma unroll
        for (int ks = 0; ks < 4; ++ks)
            dcv[ks] = *(const f16x8*)(s_df16 + ks*32 + lgrp*8);
        const f16 dn0h = s_df16[n0];
        const f16 dn1h = s_df16[n1];

        f32x4 acc[2][2];                     // [rt=fo][ct=n]
        #pragma unroll
        for (int rt = 0; rt < 2; ++rt)
        #pragma unroll
        for (int ct = 0; ct < 2; ++ct)
            acc[rt][ct] = (f32x4){0.f,0.f,0.f,0.f};
        float rs0 = 0.f, rs1 = 0.f;
        #pragma unroll
        for (int ks = 0; ks < 4; ++ks) {
            const int ko = ks*32 + lgrp*8;
            f16x8 A0 = *(const f16x8*)(U + r0*SP + ko) * dcv[ks];
            f16x8 A1 = *(const f16x8*)(U + r1*SP + ko) * dcv[ks];
            f16x8 B0 = *(const f16x8*)(Gc + n0*SP + ko);
            f16x8 B1 = *(const f16x8*)(Gc + n1*SP + ko);
            acc[0][0] = mm(A0, B0, acc[0][0]);
            acc[0][1] = mm(A0, B1, acc[0][1]);
            acc[1][0] = mm(A1, B0, acc[1][0]);
            acc[1][1] = mm(A1, B1, acc[1][1]);
            if (ks == wr) {                  // own (n in wc, k in wr) quarter
                f16x8 G0s = B0 * dcv[ks] * dn0h;
                f16x8 G1s = B1 * dcv[ks] * dn1h;
                *(f16x8*)(Gn + n0*SP + ko) = G0s;
                *(f16x8*)(Gn + n1*SP + ko) = G1s;
                rs0 = rowdot8(G0s, rs0);
                rs1 = rowdot8(G1s, rs1);
            }
        }
        rs0 += __shfl_xor(rs0, 16); rs0 += __shfl_xor(rs0, 32);
        rs1 += __shfl_xor(rs1, 16); rs1 += __shfl_xor(rs1, 32);
        if (lgrp == 0) {
            s_rows[wr*NN + n0] = rs0;
            s_rows[wr*NN + n1] = rs1;
        }

        // epilogue: z = dn * acc + bias(fo), relu; f16x4 -> X; ssq
        const float dn[2] = { s_d[n0], s_d[n1] };
        float ssc[2] = {0.f, 0.f};
        #pragma unroll
        for (int rt = 0; rt < 2; ++rt)
        #pragma unroll
        for (int ct = 0; ct < 2; ++ct) {
            f16x4 xv;
            #pragma unroll
            for (int q = 0; q < 4; ++q) {
                float bq = rt ? ((const float*)&bv1)[q] : ((const float*)&bv0)[q];
                float zv = fmaxf(fmaf(dn[ct], acc[rt][ct][q], bq), 0.f);
                ssc[ct] = fmaf(zv, zv, ssc[ct]);
                xv[q] = (f16)zv;
            }
            *(f16x4*)(X + (wc*32 + ct*16 + lrow)*SP + wr*32 + rt*16 + lgrp*4) = xv;
        }
        ssc[0] += __shfl_xor(ssc[0], 16); ssc[0] += __shfl_xor(ssc[0], 32);
        ssc[1] += __shfl_xor(ssc[1], 16); ssc[1] += __shfl_xor(ssc[1], 32);
        if (lgrp == 0) {
            s_ssq[wr*NN + n0] = ssc[0];
            s_ssq[wr*NN + n1] = ssc[1];
        }
        __syncthreads();

        // ========== P4: mm_a (dv-scaled) + t<128 tail ==========
        float p_keep = 0.f;
        if (pn < NN) {
            f16 dvh[2];
            #pragma unroll
            for (int rt = 0; rt < 2; ++rt) {
                const int row = wr*32 + rt*16 + lrow;
                float sq = s_ssq[row] + s_ssq[NN+row] + s_ssq[2*NN+row] + s_ssq[3*NN+row];
                float dv = (i == 0) ? 1.f : 1.f/(sqrtf(sq) + 1e-8f);
                dvh[rt] = (f16)fminf(dv, 60000.f);
            }
            run_mma(dvh[0], dvh[1]);

            if (t < NN) {
                const int tt = t;
                f16* GnP = Gn;
                float sqp = s_ssq[pn] + s_ssq[NN+pn] + s_ssq[2*NN+pn] + s_ssq[3*NN+pn];
                float dp = (i == 0) ? 1.f : 1.f/(sqrtf(sqp) + 1e-8f);
                if (tt < pn) {
                    const f16x8* Xr = (const f16x8*)(X + tt*SP);
                    const f16x8* Xp = (const f16x8*)(X + pn*SP);
                    float a0 = 0.f, a1 = 0.f, a2v = 0.f, a3 = 0.f;
                    #pragma unroll
                    for (int c = 0; c < 4; ++c) {
                        a0  = dot8(Xr[c*4 + 0], Xp[c*4 + 0], a0);
                        a1  = dot8(Xr[c*4 + 1], Xp[c*4 + 1], a1);
                        a2v = dot8(Xr[c*4 + 2], Xp[c*4 + 2], a2v);
                        a3  = dot8(Xr[c*4 + 3], Xp[c*4 + 3], a3);
                    }
                    float zd = (a0 + a1) + (a2v + a3);
                    float sqj = s_ssq[tt] + s_ssq[NN+tt] + s_ssq[2*NN+tt] + s_ssq[3*NN+tt];
                    float dj = (i == 0) ? 1.f : 1.f/(sqrtf(sqj) + 1e-8f);
                    p_keep = 1.f/(1.f + expf(-0.5f*zd*dj*dp));
                    f16 pf = (f16)p_keep;
                    outb[pn*NN + tt] = p_keep;
                    outb[tt*NN + pn] = p_keep;
                    GnP[pn*SP + tt] = pf;     // patch row pn
                    GnP[tt*SP + pn] = pf;     // patch col pn
                }
                s_prob[tt] = p_keep;
            }
        }
        __syncthreads();

        // ========== P4c: degrees/diag (t<128) ==========
        if (pn < NN && t < NN) {
            const int tt = t;
            float pa = s_prob[lane];
            float pb = s_prob[lane + 64];
            float sp = ((lane < pn) ? pa : 0.f) + ((lane + 64 < pn) ? pb : 0.f);
            #pragma unroll
            for (int m2 = 1; m2 < 64; m2 <<= 1) sp += __shfl_xor(sp, m2);
            // rowsum(C_i) = local (carry diag auto-correct with +I fold)
            float rsC = s_rows[tt] + s_rows[NN+tt] + s_rows[2*NN+tt] + s_rows[3*NN+tt];
            float dgC = s_diag[tt];                   // diag(C_i)_t
            float rsM = (tt < pn) ? (rsC + p_keep)
                      : ((tt == pn) ? (sp + dgC) : rsC);
            float dnew = 1.f/sqrtf(rsM + 1.f + 1e-8f);
            s_d[tt] = dnew;
            s_df16[tt] = (f16)dnew;
            s_diag[tt] = dnew*dnew*(dgC + 1.f);       // diag(C_{i+1})
            Gn[tt*SP + tt] = (f16)(dgC + 1.f);        // stored diag = dgC+1
        }
        __syncthreads();
    }
}

extern "C" void kernel_launch(void* const* d_in, const int* in_sizes, int n_in,
                              void* d_out, int out_size, void* d_ws, size_t ws_size,
                              hipStream_t stream) {
    const float* x  = (const float*)d_in[0];
    const float* W  = (const float*)d_in[1];
    const float* bb = (const float*)d_in[2];
    float* out = (float*)d_out;

    const size_t shmem = (size_t)(4*NN*SP + NN)*sizeof(f16)
                       + (size_t)(3*NN + 4*NN + 4*NN)*sizeof(float);
    hipFuncSetAttribute((const void*)gcn_gen_kernel,
                        hipFuncAttributeMaxDynamicSharedMemorySize, (int)shmem);
    gcn_gen_kernel<<<8, 1024, shmem, stream>>>(x, W, bb, out);
}